// Round 5
// baseline (1038.382 us; speedup 1.0000x reference)
//
#include <hip/hip_runtime.h>
#include <cstdint>
#include <cstddef>

// Problem constants (match reference setup_inputs)
#define Bb   256
#define Tt   250
#define DIN  700
#define Hh   128
#define DOUT 20

typedef float f32x4 __attribute__((ext_vector_type(4)));

// ---------------------------------------------------------------------------
// Phase 1: gemm, EXACT R0 compute. ONLY the epilogue changed: output stored
// TRANSPOSED as H1T[h][b*T+t] (stride 64000) so phase 2 reads each unit's
// time series stride-1. Same FMA order => bit-identical values.
// ---------------------------------------------------------------------------
constexpr int BM  = 128;
constexpr int BK  = 20;
constexpr int BN  = 128;
constexpr int BMP = BM + 4;
constexpr int MTOT = Bb * Tt;   // 64000

__device__ __forceinline__ int bswz(int g) { return g ^ (g >> 3); }

__global__ __launch_bounds__(256, 2) void gemm_h1(const float* __restrict__ x,
                                                  const float* __restrict__ W1,
                                                  const float* __restrict__ b1,
                                                  float* __restrict__ H1T) {
    __shared__ float Ast[BK][BMP];
    __shared__ float Bs[BK][BN];

    const int tid = threadIdx.x;
    const int tx  = tid & 15;
    const int ty  = tid >> 4;
    const int m0  = blockIdx.x * BM;

    const int c0 = bswz(tx * 2) * 4;
    const int c1 = bswz(tx * 2 + 1) * 4;

    float acc[8][8];
#pragma unroll
    for (int r = 0; r < 8; ++r)
#pragma unroll
        for (int c = 0; c < 8; ++c) acc[r][c] = 0.f;

    for (int k0 = 0; k0 < DIN; k0 += BK) {
#pragma unroll
        for (int idx = tid; idx < 640; idx += 256) {
            int row = idx / 5;
            int kq  = (idx - row * 5) * 4;
            const float4 v =
                *(const float4*)&x[(size_t)(m0 + row) * DIN + (k0 + kq)];
            Ast[kq + 0][row] = v.x;
            Ast[kq + 1][row] = v.y;
            Ast[kq + 2][row] = v.z;
            Ast[kq + 3][row] = v.w;
        }
#pragma unroll
        for (int idx = tid; idx < 640; idx += 256) {
            int kr = idx >> 5;
            int g  = idx & 31;
            *(float4*)&Bs[kr][bswz(g) * 4] =
                *(const float4*)&W1[(size_t)(k0 + kr) * BN + g * 4];
        }
        __syncthreads();

#pragma unroll
        for (int kk = 0; kk < BK; ++kk) {
            float a[8], bv[8];
            *(float4*)&a[0]  = *(const float4*)&Ast[kk][ty * 8];
            *(float4*)&a[4]  = *(const float4*)&Ast[kk][ty * 8 + 4];
            *(float4*)&bv[0] = *(const float4*)&Bs[kk][c0];
            *(float4*)&bv[4] = *(const float4*)&Bs[kk][c1];
#pragma unroll
            for (int r = 0; r < 8; ++r)
#pragma unroll
                for (int c = 0; c < 8; ++c)
                    acc[r][c] = fmaf(a[r], bv[c], acc[r][c]);
        }
        __syncthreads();
    }

    // Transposed epilogue: H1T[(tx*8+c)*64000 + m0 + ty*8 + r] = acc[r][c]+b1
#pragma unroll
    for (int c = 0; c < 8; ++c) {
        const float bbc = b1[tx * 8 + c];
        float4 lo, hi;
        lo.x = acc[0][c] + bbc; lo.y = acc[1][c] + bbc;
        lo.z = acc[2][c] + bbc; lo.w = acc[3][c] + bbc;
        hi.x = acc[4][c] + bbc; hi.y = acc[5][c] + bbc;
        hi.z = acc[6][c] + bbc; hi.w = acc[7][c] + bbc;
        const size_t base = (size_t)(tx * 8 + c) * MTOT + (m0 + ty * 8);
        *(float4*)&H1T[base]     = lo;
        *(float4*)&H1T[base + 4] = hi;
    }
}

// ---------------------------------------------------------------------------
// Phase 2: recurrence, waitcnt-sanitized.
// Theory (R4 post-mortem): R0-R3 were all ~230us because gather results were
// consumed UNCONDITIONALLY each step -> compiler-inserted conservative
// s_waitcnt (vmcnt/lgkmcnt 0) every step drained the h1 prefetch pipeline,
// exposing a memory round trip per step regardless of spike count.
// Fix: the no-spike steady path touches NO memory:
//  - h1 via inline-asm global_load_dwordx4 into 4 rotating reg slots
//    (4 steps/slot, issued 3 groups ahead, counted WAITV(4)+sched_barrier
//    at 4-step boundaries only). Compiler never auto-waits on these.
//  - layer-1 gather from LDS weights, consumed in-branch; u1g apply guarded
//    by wave-uniform sp1 flag (skipping a +0.0f add: exact).
//  - layer-2 rcW2 via inline-asm dword loads issued in-branch at step t,
//    applied inside if(df) at t+1 (WAITV(0) lives in the rare branch).
// Term order of every sum matches R3 (verified absmax 0.0).
// npass: diagnostic repeat count (state re-inits per pass; output written
// from last pass -> npass=1 launch (last) produces the correct result).
// ---------------------------------------------------------------------------

#define WAITV(N)                                                       \
    asm volatile("s_waitcnt vmcnt(" #N ")" ::: "memory");              \
    __builtin_amdgcn_sched_barrier(0)

#define LOADD(D, P)                                                    \
    asm volatile("global_load_dword %0, %1, off"                       \
                 : "=&v"(D) : "v"(P) : "memory");

#define ISSUE(SL, SH, TB)                                              \
    {                                                                  \
        int tb_ = (TB); tb_ = (tb_ > 246) ? 246 : tb_;                 \
        asm volatile("global_load_dwordx4 %0, %2, off\n\t"             \
                     "global_load_dwordx4 %1, %3, off"                 \
                     : "=&v"(SL), "=&v"(SH)                            \
                     : "v"(pl + tb_), "v"(ph + tb_) : "memory");       \
    }

__device__ __forceinline__ void gll16(const void* g, void* l) {
    __builtin_amdgcn_global_load_lds(
        (const __attribute__((address_space(1))) uint32_t*)g,
        (__attribute__((address_space(3))) uint32_t*)l, 16, 0, 0);
}

#define EXTR(K)                                                        \
    if (mlo) { K = (int)__ffsll(mlo) - 1; mlo &= mlo - 1ull; }         \
    else     { K = 64 + (int)__ffsll(mhi) - 1; mhi &= mhi - 1ull; }
#define EXTR2(K)                                                       \
    if (mlo)      { K = (int)__ffsll(mlo) - 1; mlo &= mlo - 1ull; }    \
    else if (mhi) { K = 64 + (int)__ffsll(mhi) - 1; mhi &= mhi - 1ull; }

__global__ __launch_bounds__(64) void recurrent(
    const float* __restrict__ H1T,  const float* __restrict__ rcW1,
    const float* __restrict__ rcb1, const float* __restrict__ W2,
    const float* __restrict__ b2,   const float* __restrict__ rcW2,
    const float* __restrict__ rcb2, const float* __restrict__ W3,
    const float* __restrict__ b3,   float* __restrict__ out, int npass) {

    __shared__ float W2ls[Hh * Hh];    // 64 KB
    __shared__ float rcW1ls[Hh * Hh];  // 64 KB

    const int lane = threadIdx.x;     // 0..63
    const int b    = blockIdx.x;

    const float rcb1x = rcb1[lane], rcb1y = rcb1[lane + 64];
    const float bb2x  = b2[lane]      + rcb2[lane];
    const float bb2y  = b2[lane + 64] + rcb2[lane + 64];

    // per-lane time-series base pointers (units lane, lane+64)
    const float* pl = H1T + (size_t)lane * MTOT + (size_t)b * Tt;
    const float* ph = H1T + (size_t)(lane + 64) * MTOT + (size_t)b * Tt;

    // one-time async weight preload (in flight under first prologue WAITV)
    {
        const char* g2 = (const char*)W2 + lane * 16;
        const char* g1 = (const char*)rcW1 + lane * 16;
        char* l2 = (char*)W2ls;
        char* l1 = (char*)rcW1ls;
#pragma unroll 1
        for (int i = 0; i < 64; ++i) gll16(g2 + (size_t)i * 1024, l2 + i * 1024);
#pragma unroll 1
        for (int i = 0; i < 64; ++i) gll16(g1 + (size_t)i * 1024, l1 + i * 1024);
    }

    float cntx = 0.f, cnty = 0.f;

#pragma unroll 1
    for (int pass = 0; pass < npass; ++pass) {
        float v1x = 0.f, v1y = 0.f, v2x = 0.f, v2y = 0.f;
        cntx = 0.f; cnty = 0.f;
        float u1gx = 0.f, u1gy = 0.f;
        float dl0x = 0.f, dl0y = 0.f, dl1x = 0.f, dl1y = 0.f,
              dl2x = 0.f, dl2y = 0.f;
        bool sp1 = false, df = false, f1 = false, f2 = false;

        f32x4 sa_l, sa_h, sb_l, sb_h, sc_l, sc_h, sd_l, sd_h;

        // prologue: groups 0,1,2 -> slots a,b,c
        ISSUE(sa_l, sa_h, 0)
        ISSUE(sb_l, sb_h, 4)
        ISSUE(sc_l, sc_h, 8)
        WAITV(4);   // (pass 0: also forces weight preload complete)

#define STEP(SL, SH, C)                                                       \
    {                                                                         \
        /* ---- LIF 1 ---- */                                                 \
        float u1x = SL.C + rcb1x;                                             \
        float u1y = SH.C + rcb1y;                                             \
        if (sp1) { u1x += u1gx; u1y += u1gy; }                                \
        v1x = v1x + (u1x - v1x) * 0.5f;                                       \
        v1y = v1y + (u1y - v1y) * 0.5f;                                       \
        const bool s1x = (v1x >= 1.0f);                                       \
        const bool s1y = (v1y >= 1.0f);                                       \
        if (s1x) v1x = 0.f;                                                   \
        if (s1y) v1y = 0.f;                                                   \
        const unsigned long long a0 = __ballot((int)s1x);                     \
        const unsigned long long a1 = __ballot((int)s1y);                     \
        float uW2x = 0.f, uW2y = 0.f;                                         \
        sp1 = ((a0 | a1) != 0ull);                                            \
        if (sp1) { /* layer-1 fanout from LDS, 4-wide, ascending k */         \
            float g1x = 0.f, g1y = 0.f;                                       \
            unsigned long long mlo = a0, mhi = a1;                            \
            while (mlo | mhi) {                                               \
                int k0; int k1 = -1; int k2 = -1; int k3 = -1;                \
                EXTR(k0) EXTR2(k1) EXTR2(k2) EXTR2(k3)                        \
                const int i0 = k0 << 7;                                       \
                const int i1 = (k1 >= 0 ? k1 : k0) << 7;                      \
                const int i2 = (k2 >= 0 ? k2 : k0) << 7;                      \
                const int i3 = (k3 >= 0 ? k3 : k0) << 7;                      \
                const float w0x = W2ls[i0 + lane],   w0y = W2ls[i0 + 64 + lane];   \
                const float r0x = rcW1ls[i0 + lane], r0y = rcW1ls[i0 + 64 + lane]; \
                const float w1x = W2ls[i1 + lane],   w1y = W2ls[i1 + 64 + lane];   \
                const float r1x = rcW1ls[i1 + lane], r1y = rcW1ls[i1 + 64 + lane]; \
                const float w2x = W2ls[i2 + lane],   w2y = W2ls[i2 + 64 + lane];   \
                const float r2x = rcW1ls[i2 + lane], r2y = rcW1ls[i2 + 64 + lane]; \
                const float w3x = W2ls[i3 + lane],   w3y = W2ls[i3 + 64 + lane];   \
                const float r3x = rcW1ls[i3 + lane], r3y = rcW1ls[i3 + 64 + lane]; \
                uW2x += w0x; uW2y += w0y; g1x += r0x; g1y += r0y;             \
                if (k1 >= 0) { uW2x += w1x; uW2y += w1y; g1x += r1x; g1y += r1y; } \
                if (k2 >= 0) { uW2x += w2x; uW2y += w2y; g1x += r2x; g1y += r2y; } \
                if (k3 >= 0) { uW2x += w3x; uW2y += w3y; g1x += r3x; g1y += r3y; } \
            }                                                                 \
            u1gx = g1x; u1gy = g1y;                                           \
        }                                                                     \
        /* ---- LIF 2 (deferred rcW2 apply, in-branch wait) ---- */           \
        float u2x = bb2x + uW2x;                                              \
        float u2y = bb2y + uW2y;                                              \
        if (df) {                                                             \
            WAITV(0);                                                         \
            const float ax = (dl0x + (f1 ? dl1x : 0.f)) + (f2 ? dl2x : 0.f);  \
            const float ay = (dl0y + (f1 ? dl1y : 0.f)) + (f2 ? dl2y : 0.f);  \
            u2x += ax; u2y += ay;                                             \
        }                                                                     \
        v2x = v2x + (u2x - v2x) * 0.5f;                                       \
        v2y = v2y + (u2y - v2y) * 0.5f;                                       \
        const bool s2x = (v2x >= 1.0f);                                       \
        const bool s2y = (v2y >= 1.0f);                                       \
        if (s2x) v2x = 0.f;                                                   \
        if (s2y) v2y = 0.f;                                                   \
        cntx += s2x ? 1.f : 0.f;                                              \
        cnty += s2y ? 1.f : 0.f;                                              \
        const unsigned long long c0m = __ballot((int)s2x);                    \
        const unsigned long long c1m = __ballot((int)s2y);                    \
        df = false; f1 = false; f2 = false;                                   \
        if (c0m | c1m) { /* issue now, apply next step */                     \
            unsigned long long mlo = c0m, mhi = c1m;                          \
            const int n2 = __popcll(c0m) + __popcll(c1m);                     \
            if (n2 <= 3) {                                                    \
                int k0; int k1 = -1; int k2 = -1;                             \
                EXTR(k0) EXTR2(k1) EXTR2(k2)                                  \
                const float* p0 = rcW2 + ((size_t)k0 << 7);                   \
                const float* p1 = rcW2 + ((size_t)(k1 >= 0 ? k1 : k0) << 7);  \
                const float* p2 = rcW2 + ((size_t)(k2 >= 0 ? k2 : k0) << 7);  \
                LOADD(dl0x, p0 + lane)  LOADD(dl0y, p0 + lane + 64)           \
                LOADD(dl1x, p1 + lane)  LOADD(dl1y, p1 + lane + 64)           \
                LOADD(dl2x, p2 + lane)  LOADD(dl2y, p2 + lane + 64)           \
                df = true; f1 = (k1 >= 0); f2 = (k2 >= 0);                    \
            } else { /* rare: in-step ascending walk (plain loads) */         \
                float sx = 0.f, sy = 0.f;                                     \
                while (mlo | mhi) {                                           \
                    int kk; EXTR(kk)                                          \
                    const float* pr = rcW2 + ((size_t)kk << 7);               \
                    sx += pr[lane]; sy += pr[lane + 64];                      \
                }                                                             \
                dl0x = sx; dl0y = sy;                                         \
                df = true; /* f1,f2 false: apply adds exact +0.0f */          \
            }                                                                 \
        }                                                                     \
    }

#define GROUP(CL, CH, IL, IH, G)                                              \
        ISSUE(IL, IH, 4 * ((G) + 3))                                          \
        WAITV(4);                                                             \
        STEP(CL, CH, x) STEP(CL, CH, y) STEP(CL, CH, z) STEP(CL, CH, w)

        // groups 0..59 (15 quads), slot(g) = g%4, issue target = (g+3)%4
#pragma unroll 1
        for (int i = 0; i < 15; ++i) {
            const int G = i * 4;
            GROUP(sa_l, sa_h, sd_l, sd_h, G)
            GROUP(sb_l, sb_h, sa_l, sa_h, G + 1)
            GROUP(sc_l, sc_h, sb_l, sb_h, G + 2)
            GROUP(sd_l, sd_h, sc_l, sc_h, G + 3)
        }
        // groups 60,61 (issues are clamped dummies), then partial group 62:
        // slot c was loaded at entry of g59 with clamped base t=246, so
        // t=248 -> .z, t=249 -> .w.
        GROUP(sa_l, sa_h, sd_l, sd_h, 60)
        GROUP(sb_l, sb_h, sa_l, sa_h, 61)
        WAITV(0);
        STEP(sc_l, sc_h, z)
        STEP(sc_l, sc_h, w)
#undef GROUP
#undef STEP
    }

    // ---- readout: out[b] = cnt2 @ W3 + T*b3 (reuse W2ls as scratch) ----
    __syncthreads();
    W2ls[lane]      = cntx;
    W2ls[lane + 64] = cnty;
    __syncthreads();
    if (lane < DOUT) {
        float o = (float)Tt * b3[lane];
#pragma unroll 8
        for (int k = 0; k < Hh; ++k) o += W2ls[k] * W3[k * DOUT + lane];
        out[b * DOUT + lane] = o;
    }
}

// ---------------------------------------------------------------------------
extern "C" void kernel_launch(void* const* d_in, const int* in_sizes, int n_in,
                              void* d_out, int out_size, void* d_ws, size_t ws_size,
                              hipStream_t stream) {
    const float* x    = (const float*)d_in[0];
    const float* W1   = (const float*)d_in[1];
    const float* b1   = (const float*)d_in[2];
    const float* rcW1 = (const float*)d_in[3];
    const float* rcb1 = (const float*)d_in[4];
    const float* W2   = (const float*)d_in[5];
    const float* b2   = (const float*)d_in[6];
    const float* rcW2 = (const float*)d_in[7];
    const float* rcb2 = (const float*)d_in[8];
    const float* W3   = (const float*)d_in[9];
    const float* b3   = (const float*)d_in[10];

    float* out = (float*)d_out;
    float* H1T = (float*)d_ws;   // 128 x 64000 f32 = 32.77 MB (transposed)

    gemm_h1<<<(Bb * Tt) / BM, 256, 0, stream>>>(x, W1, b1, H1T);
    // Diagnostic: 12 internal passes (garbage out, exact per-pass timing in
    // rocprof). Real pass runs LAST and rewrites all outputs -> absmax 0.0.
    recurrent<<<Bb, 64, 0, stream>>>(H1T, rcW1, rcb1, W2, b2, rcW2, rcb2, W3,
                                     b3, out, 12);
    recurrent<<<Bb, 64, 0, stream>>>(H1T, rcW1, rcb1, W2, b2, rcW2, rcb2, W3,
                                     b3, out, 1);
}

// Round 6
// 463.459 us; speedup vs baseline: 2.2405x; 2.2405x over previous
//
#include <hip/hip_runtime.h>
#include <cstdint>
#include <cstddef>

// Problem constants (match reference setup_inputs)
#define Bb   256
#define Tt   250
#define DIN  700
#define Hh   128
#define DOUT 20

// ---------------------------------------------------------------------------
// Phase 1: EXACT R0 gemm (218 us, VGPR 92, verified). Do not touch.
// H1 layout [b*T+t][h] row-major (required by phase-2 ring).
// ---------------------------------------------------------------------------
constexpr int BM  = 128;
constexpr int BK  = 20;
constexpr int BN  = 128;
constexpr int BMP = BM + 4;

__device__ __forceinline__ int bswz(int g) { return g ^ (g >> 3); }

__global__ __launch_bounds__(256, 2) void gemm_h1(const float* __restrict__ x,
                                                  const float* __restrict__ W1,
                                                  const float* __restrict__ b1,
                                                  float* __restrict__ H1) {
    __shared__ float Ast[BK][BMP];
    __shared__ float Bs[BK][BN];

    const int tid = threadIdx.x;
    const int tx  = tid & 15;
    const int ty  = tid >> 4;
    const int m0  = blockIdx.x * BM;

    const int c0 = bswz(tx * 2) * 4;
    const int c1 = bswz(tx * 2 + 1) * 4;

    float acc[8][8];
#pragma unroll
    for (int r = 0; r < 8; ++r)
#pragma unroll
        for (int c = 0; c < 8; ++c) acc[r][c] = 0.f;

    for (int k0 = 0; k0 < DIN; k0 += BK) {
#pragma unroll
        for (int idx = tid; idx < 640; idx += 256) {
            int row = idx / 5;
            int kq  = (idx - row * 5) * 4;
            const float4 v =
                *(const float4*)&x[(size_t)(m0 + row) * DIN + (k0 + kq)];
            Ast[kq + 0][row] = v.x;
            Ast[kq + 1][row] = v.y;
            Ast[kq + 2][row] = v.z;
            Ast[kq + 3][row] = v.w;
        }
#pragma unroll
        for (int idx = tid; idx < 640; idx += 256) {
            int kr = idx >> 5;
            int g  = idx & 31;
            *(float4*)&Bs[kr][bswz(g) * 4] =
                *(const float4*)&W1[(size_t)(k0 + kr) * BN + g * 4];
        }
        __syncthreads();

#pragma unroll
        for (int kk = 0; kk < BK; ++kk) {
            float a[8], bv[8];
            *(float4*)&a[0]  = *(const float4*)&Ast[kk][ty * 8];
            *(float4*)&a[4]  = *(const float4*)&Ast[kk][ty * 8 + 4];
            *(float4*)&bv[0] = *(const float4*)&Bs[kk][c0];
            *(float4*)&bv[4] = *(const float4*)&Bs[kk][c1];
#pragma unroll
            for (int r = 0; r < 8; ++r)
#pragma unroll
                for (int c = 0; c < 8; ++c)
                    acc[r][c] = fmaf(a[r], bv[c], acc[r][c]);
        }
        __syncthreads();
    }

    float bb[8];
#pragma unroll
    for (int c = 0; c < 8; ++c) bb[c] = b1[tx * 8 + c];

#pragma unroll
    for (int r = 0; r < 8; ++r) {
        size_t row = (size_t)(m0 + ty * 8 + r);
        float4 o0, o1;
        o0.x = acc[r][0] + bb[0]; o0.y = acc[r][1] + bb[1];
        o0.z = acc[r][2] + bb[2]; o0.w = acc[r][3] + bb[3];
        o1.x = acc[r][4] + bb[4]; o1.y = acc[r][5] + bb[5];
        o1.z = acc[r][6] + bb[6]; o1.w = acc[r][7] + bb[7];
        *(float4*)&H1[row * Hh + tx * 8]     = o0;
        *(float4*)&H1[row * Hh + tx * 8 + 4] = o1;
    }
}

// ---------------------------------------------------------------------------
// Phase 2: recurrence = verified R3 machinery + R5's conditional consumption.
// R5 proved (601us/12 passes = 50us/pass) that guarding gather consumption
// with wave-uniform flags removes the per-step compiler waitcnt drain (the
// real R0-R3 bottleneck). R5's absmax=0.125 came from raw-register inline-asm
// loads pending across C statements / the loop back-edge (RA copies can read
// a VGPR before the load retires). Fix: NO register-destined asm loads.
//  - h1 via the R2/R3-verified LDS ring (global_load_lds + counted WAITV(8)
//    at 8-step chunk boundaries; LDS destination => no register hazard).
//  - layer-1 gather from LDS weights (W2+rcW1, 128 KB), consumed only under
//    sp1 (= "layer-1 spiked last step"); compiler-managed lgkmcnt in-branch.
//  - layer-2 rcW2 deferred gather: plain-C loads issued at step t, consumed
//    at t+1 ONLY under df; compiler places its (counted) vmcnt wait inside
//    the rare branch and is fully aware of the pending loads. Safe.
// All sums keep R3's term order; guards skip exact +0.0f adds => absmax 0.0.
// ---------------------------------------------------------------------------

#define WAITV(N)                                                       \
    asm volatile("s_waitcnt vmcnt(" #N ")" ::: "memory");              \
    __builtin_amdgcn_sched_barrier(0)

__device__ __forceinline__ void gll16(const void* g, void* l) {
    __builtin_amdgcn_global_load_lds(
        (const __attribute__((address_space(1))) uint32_t*)g,
        (__attribute__((address_space(3))) uint32_t*)l, 16, 0, 0);
}

// Chunk c covers steps [8c, 8c+8); 4 instrs x 1024 B (chunk 31: 1 instr).
// hg already includes lane*16.
__device__ __forceinline__ void issue_chunk(const char* hg, char* ringb,
                                            int c, int n) {
    const char* g = hg + (size_t)c * 4096;
    char* l = ringb + (c & 3) * 4096;
    for (int i = 0; i < n; ++i) gll16(g + (size_t)i * 1024, l + i * 1024);
}

#define EXTR(K)                                                        \
    if (mlo) { K = (int)__ffsll(mlo) - 1; mlo &= mlo - 1ull; }         \
    else     { K = 64 + (int)__ffsll(mhi) - 1; mhi &= mhi - 1ull; }
#define EXTR2(K)                                                       \
    if (mlo)      { K = (int)__ffsll(mlo) - 1; mlo &= mlo - 1ull; }    \
    else if (mhi) { K = 64 + (int)__ffsll(mhi) - 1; mhi &= mhi - 1ull; }

__global__ __launch_bounds__(64) void recurrent(
    const float* __restrict__ H1,   const float* __restrict__ rcW1,
    const float* __restrict__ rcb1, const float* __restrict__ W2,
    const float* __restrict__ b2,   const float* __restrict__ rcW2,
    const float* __restrict__ rcb2, const float* __restrict__ W3,
    const float* __restrict__ b3,   float* __restrict__ out) {

    __shared__ float W2ls[Hh * Hh];    // 64 KB
    __shared__ float rcW1ls[Hh * Hh];  // 64 KB
    __shared__ float ring[32 * Hh];    // 16 KB: 32 steps x 128 floats

    const int lane = threadIdx.x;     // 0..63
    const int b    = blockIdx.x;

    const float rcb1x = rcb1[lane], rcb1y = rcb1[lane + 64];
    const float bb2x  = b2[lane]      + rcb2[lane];
    const float bb2y  = b2[lane + 64] + rcb2[lane + 64];
    const float* __restrict__ h1p = H1 + (size_t)b * Tt * Hh;

    // async preload: W2, rcW1 -> LDS (linear copies), then ring chunks 0..2
    {
        const char* g2 = (const char*)W2 + lane * 16;
        const char* g1 = (const char*)rcW1 + lane * 16;
        char* l2 = (char*)W2ls;
        char* l1 = (char*)rcW1ls;
#pragma unroll 1
        for (int i = 0; i < 64; ++i) gll16(g2 + (size_t)i * 1024, l2 + i * 1024);
#pragma unroll 1
        for (int i = 0; i < 64; ++i) gll16(g1 + (size_t)i * 1024, l1 + i * 1024);
    }
    const char* hg = (const char*)h1p + lane * 16;
    char* ringb = (char*)ring;
    issue_chunk(hg, ringb, 0, 4);
    issue_chunk(hg, ringb, 1, 4);
    issue_chunk(hg, ringb, 2, 4);
    WAITV(4);   // weights + chunks 0,1 retired (in-order); chunk 2 in flight

    float v1x = 0.f, v1y = 0.f, v2x = 0.f, v2y = 0.f;
    float cntx = 0.f, cnty = 0.f;
    float u1gx = 0.f, u1gy = 0.f;     // rcW1 gather (valid iff sp1)
    float l0x = 0.f, l0y = 0.f, l1x = 0.f, l1y = 0.f, l2x = 0.f, l2y = 0.f;
    bool  sp1 = false, df = false, f1 = false, f2 = false;

    // 4-deep register pipeline (slot j holds step t with t%4==j), from ring
    float h1xs[4], h1ys[4];
#pragma unroll
    for (int j = 0; j < 4; ++j) {
        h1xs[j] = ring[(j << 7) + lane];
        h1ys[j] = ring[(j << 7) + lane + 64];
    }

#define STEP(T, J)                                                            \
    {                                                                         \
        const int t_ = (T);                                                   \
        /* ---- LIF 1 (consume slot J, refill it for t+4 from ring) ---- */   \
        float u1xv = h1xs[J] + rcb1x;                                         \
        float u1yv = h1ys[J] + rcb1y;                                         \
        if (sp1) { u1xv += u1gx; u1yv += u1gy; }                              \
        int tp = t_ + 4; tp = (tp < Tt) ? tp : (Tt - 1);                      \
        const float* rp_ = &ring[(tp & 31) << 7];                             \
        h1xs[J] = rp_[lane];                                                  \
        h1ys[J] = rp_[lane + 64];                                             \
        v1x = v1x + (u1xv - v1x) * 0.5f;                                      \
        v1y = v1y + (u1yv - v1y) * 0.5f;                                      \
        const bool s1x = (v1x >= 1.0f);                                       \
        const bool s1y = (v1y >= 1.0f);                                       \
        if (s1x) v1x = 0.f;                                                   \
        if (s1y) v1y = 0.f;                                                   \
        const unsigned long long a0 = __ballot((int)s1x);                     \
        const unsigned long long a1 = __ballot((int)s1y);                     \
        /* ---- layer-1 fanout from LDS, 4-wide, ascending k, in-branch */    \
        float uW2x = 0.f, uW2y = 0.f;                                         \
        sp1 = ((a0 | a1) != 0ull);                                            \
        if (sp1) {                                                            \
            float g1x = 0.f, g1y = 0.f;                                       \
            unsigned long long mlo = a0, mhi = a1;                            \
            while (mlo | mhi) {                                               \
                int k0; int k1 = -1; int k2 = -1; int k3 = -1;                \
                EXTR(k0) EXTR2(k1) EXTR2(k2) EXTR2(k3)                        \
                const int i0 = k0 << 7;                                       \
                const int i1 = (k1 >= 0 ? k1 : k0) << 7;                      \
                const int i2 = (k2 >= 0 ? k2 : k0) << 7;                      \
                const int i3 = (k3 >= 0 ? k3 : k0) << 7;                      \
                const float w0x = W2ls[i0 + lane],   w0y = W2ls[i0 + 64 + lane];   \
                const float r0x = rcW1ls[i0 + lane], r0y = rcW1ls[i0 + 64 + lane]; \
                const float w1x = W2ls[i1 + lane],   w1y = W2ls[i1 + 64 + lane];   \
                const float r1x = rcW1ls[i1 + lane], r1y = rcW1ls[i1 + 64 + lane]; \
                const float w2x = W2ls[i2 + lane],   w2y = W2ls[i2 + 64 + lane];   \
                const float r2x = rcW1ls[i2 + lane], r2y = rcW1ls[i2 + 64 + lane]; \
                const float w3x = W2ls[i3 + lane],   w3y = W2ls[i3 + 64 + lane];   \
                const float r3x = rcW1ls[i3 + lane], r3y = rcW1ls[i3 + 64 + lane]; \
                uW2x += w0x; uW2y += w0y; g1x += r0x; g1y += r0y;             \
                if (k1 >= 0) { uW2x += w1x; uW2y += w1y; g1x += r1x; g1y += r1y; } \
                if (k2 >= 0) { uW2x += w2x; uW2y += w2y; g1x += r2x; g1y += r2y; } \
                if (k3 >= 0) { uW2x += w3x; uW2y += w3y; g1x += r3x; g1y += r3y; } \
            }                                                                 \
            u1gx = g1x; u1gy = g1y;                                           \
        }                                                                     \
        /* ---- LIF 2 (deferred rcW2 apply, ONLY when df) ---- */             \
        float u2xv = bb2x + uW2x;                                             \
        float u2yv = bb2y + uW2y;                                             \
        if (df) {                                                             \
            const float ax = (l0x + (f1 ? l1x : 0.f)) + (f2 ? l2x : 0.f);     \
            const float ay = (l0y + (f1 ? l1y : 0.f)) + (f2 ? l2y : 0.f);     \
            u2xv += ax; u2yv += ay;                                           \
        }                                                                     \
        v2x = v2x + (u2xv - v2x) * 0.5f;                                      \
        v2y = v2y + (u2yv - v2y) * 0.5f;                                      \
        const bool s2x = (v2x >= 1.0f);                                       \
        const bool s2y = (v2y >= 1.0f);                                       \
        if (s2x) v2x = 0.f;                                                   \
        if (s2y) v2y = 0.f;                                                   \
        cntx += s2x ? 1.f : 0.f;                                              \
        cnty += s2y ? 1.f : 0.f;                                              \
        const unsigned long long c0m = __ballot((int)s2x);                    \
        const unsigned long long c1m = __ballot((int)s2y);                    \
        /* ---- layer-2 rcW2 gather: plain-C loads now, apply next step */    \
        df = false; f1 = false; f2 = false;                                   \
        if (c0m | c1m) {                                                      \
            unsigned long long mlo = c0m, mhi = c1m;                          \
            const int n2 = __popcll(c0m) + __popcll(c1m);                     \
            if (n2 <= 3) {                                                    \
                int k0; int k1 = -1; int k2 = -1;                             \
                EXTR(k0) EXTR2(k1) EXTR2(k2)                                  \
                const float* p0 = rcW2 + ((size_t)k0 << 7);                   \
                const float* p1 = rcW2 + ((size_t)(k1 >= 0 ? k1 : k0) << 7);  \
                const float* p2 = rcW2 + ((size_t)(k2 >= 0 ? k2 : k0) << 7);  \
                l0x = p0[lane]; l0y = p0[lane + 64];                          \
                l1x = p1[lane]; l1y = p1[lane + 64];                          \
                l2x = p2[lane]; l2y = p2[lane + 64];                          \
                df = true; f1 = (k1 >= 0); f2 = (k2 >= 0);                    \
            } else { /* rare: in-step ascending walk */                       \
                float sx = 0.f, sy = 0.f;                                     \
                while (mlo | mhi) {                                           \
                    int kk; EXTR(kk)                                          \
                    const float* pr = rcW2 + ((size_t)kk << 7);               \
                    sx += pr[lane]; sy += pr[lane + 64];                      \
                }                                                             \
                l0x = sx; l0y = sy;                                           \
                df = true; /* f1,f2 false: apply adds exact +0.0f */          \
            }                                                                 \
        }                                                                     \
    }

    // Main loop: 31 chunks x 8 steps (t=0..247), then tail 248,249.
    // vmcnt: c<=27: issue chunk c+3 (4), WAITV(8) => chunks c+2(4)+c+3(4)
    // are the only ring loads allowed outstanding => chunk c+1 retired.
    // (<=6 gather loads may interleave; they are NEWER than chunk c+1, so
    // in-order retirement still guarantees c+1 complete; the compiler emits
    // its own counted waits for the gather registers in the df branch.)
#pragma unroll 1
    for (int c = 0; c < 31; ++c) {
        if (c <= 27)      issue_chunk(hg, ringb, c + 3, 4);
        else if (c == 28) issue_chunk(hg, ringb, 31, 1);
        if (c <= 27) { WAITV(8); } else { WAITV(0); }
        const int t0 = c << 3;
#pragma unroll 1
        for (int g = 0; g < 2; ++g) {
            const int t = t0 + (g << 2);
            STEP(t + 0, 0)
            STEP(t + 1, 1)
            STEP(t + 2, 2)
            STEP(t + 3, 3)
        }
    }
    WAITV(0);
    STEP(248, 0)
    STEP(249, 1)
#undef STEP

    // ---- readout: out[b] = cnt2 @ W3 + T*b3 (ring reused as scratch) ----
    __syncthreads();
    ring[lane]      = cntx;
    ring[lane + 64] = cnty;
    __syncthreads();
    if (lane < DOUT) {
        float o = (float)Tt * b3[lane];
#pragma unroll 8
        for (int k = 0; k < Hh; ++k) o += ring[k] * W3[k * DOUT + lane];
        out[b * DOUT + lane] = o;
    }
}

// ---------------------------------------------------------------------------
extern "C" void kernel_launch(void* const* d_in, const int* in_sizes, int n_in,
                              void* d_out, int out_size, void* d_ws, size_t ws_size,
                              hipStream_t stream) {
    const float* x    = (const float*)d_in[0];
    const float* W1   = (const float*)d_in[1];
    const float* b1   = (const float*)d_in[2];
    const float* rcW1 = (const float*)d_in[3];
    const float* rcb1 = (const float*)d_in[4];
    const float* W2   = (const float*)d_in[5];
    const float* b2   = (const float*)d_in[6];
    const float* rcW2 = (const float*)d_in[7];
    const float* rcb2 = (const float*)d_in[8];
    const float* W3   = (const float*)d_in[9];
    const float* b3   = (const float*)d_in[10];

    float* out = (float*)d_out;
    float* H1  = (float*)d_ws;   // 64000 x 128 f32 = 32.77 MB

    gemm_h1<<<(Bb * Tt) / BM, 256, 0, stream>>>(x, W1, b1, H1);
    recurrent<<<Bb, 64, 0, stream>>>(H1, rcW1, rcb1, W2, b2, rcW2, rcb2, W3,
                                     b3, out);
}

// Round 7
// 462.209 us; speedup vs baseline: 2.2466x; 1.0027x over previous
//
#include <hip/hip_runtime.h>
#include <cstdint>
#include <cstddef>

// Problem constants (match reference setup_inputs)
#define Bb   256
#define Tt   250
#define DIN  700
#define Hh   128
#define DOUT 20

// ---------------------------------------------------------------------------
// Phase 1: EXACT R0 gemm (218 us, VGPR 92, verified). Do not touch.
// ---------------------------------------------------------------------------
constexpr int BM  = 128;
constexpr int BK  = 20;
constexpr int BN  = 128;
constexpr int BMP = BM + 4;

__device__ __forceinline__ int bswz(int g) { return g ^ (g >> 3); }

__global__ __launch_bounds__(256, 2) void gemm_h1(const float* __restrict__ x,
                                                  const float* __restrict__ W1,
                                                  const float* __restrict__ b1,
                                                  float* __restrict__ H1) {
    __shared__ float Ast[BK][BMP];
    __shared__ float Bs[BK][BN];

    const int tid = threadIdx.x;
    const int tx  = tid & 15;
    const int ty  = tid >> 4;
    const int m0  = blockIdx.x * BM;

    const int c0 = bswz(tx * 2) * 4;
    const int c1 = bswz(tx * 2 + 1) * 4;

    float acc[8][8];
#pragma unroll
    for (int r = 0; r < 8; ++r)
#pragma unroll
        for (int c = 0; c < 8; ++c) acc[r][c] = 0.f;

    for (int k0 = 0; k0 < DIN; k0 += BK) {
#pragma unroll
        for (int idx = tid; idx < 640; idx += 256) {
            int row = idx / 5;
            int kq  = (idx - row * 5) * 4;
            const float4 v =
                *(const float4*)&x[(size_t)(m0 + row) * DIN + (k0 + kq)];
            Ast[kq + 0][row] = v.x;
            Ast[kq + 1][row] = v.y;
            Ast[kq + 2][row] = v.z;
            Ast[kq + 3][row] = v.w;
        }
#pragma unroll
        for (int idx = tid; idx < 640; idx += 256) {
            int kr = idx >> 5;
            int g  = idx & 31;
            *(float4*)&Bs[kr][bswz(g) * 4] =
                *(const float4*)&W1[(size_t)(k0 + kr) * BN + g * 4];
        }
        __syncthreads();

#pragma unroll
        for (int kk = 0; kk < BK; ++kk) {
            float a[8], bv[8];
            *(float4*)&a[0]  = *(const float4*)&Ast[kk][ty * 8];
            *(float4*)&a[4]  = *(const float4*)&Ast[kk][ty * 8 + 4];
            *(float4*)&bv[0] = *(const float4*)&Bs[kk][c0];
            *(float4*)&bv[4] = *(const float4*)&Bs[kk][c1];
#pragma unroll
            for (int r = 0; r < 8; ++r)
#pragma unroll
                for (int c = 0; c < 8; ++c)
                    acc[r][c] = fmaf(a[r], bv[c], acc[r][c]);
        }
        __syncthreads();
    }

    float bb[8];
#pragma unroll
    for (int c = 0; c < 8; ++c) bb[c] = b1[tx * 8 + c];

#pragma unroll
    for (int r = 0; r < 8; ++r) {
        size_t row = (size_t)(m0 + ty * 8 + r);
        float4 o0, o1;
        o0.x = acc[r][0] + bb[0]; o0.y = acc[r][1] + bb[1];
        o0.z = acc[r][2] + bb[2]; o0.w = acc[r][3] + bb[3];
        o1.x = acc[r][4] + bb[4]; o1.y = acc[r][5] + bb[5];
        o1.z = acc[r][6] + bb[6]; o1.w = acc[r][7] + bb[7];
        *(float4*)&H1[row * Hh + tx * 8]     = o0;
        *(float4*)&H1[row * Hh + tx * 8 + 4] = o1;
    }
}

// ---------------------------------------------------------------------------
// Phase 2: recurrence.
// Ledger (R0..R6): every variant with a compiler-visible (plain-C) global
// load inside the step loop runs ~225-245us; every variant without one runs
// 25-50us/pass (rec_skel, rec_stream, R5). The guards/delivery/batching were
// never the lever - the in-loop plain-C global load is the poison.
// This round: the ONLY global access forms in the loop are
//   (1) global_load_lds ring (hand-counted vmcnt, proven cheap), and
//   (2) layer-2 rcW2 gathers as inline-asm blocks where the loads AND their
//       s_waitcnt vmcnt(0) are fused in ONE asm block -> destination regs
//       are unobservable until retired (R5's RA-copy hazard impossible).
// Layer-1 gathers stay in LDS (W2ls+rcW1ls, verified). All summation trees
// keep the R0/R6-verified left-fold ascending-k order; guards skip exact
// +0.0f terms only => absmax 0.0.
// ---------------------------------------------------------------------------

#define WAITV(N)                                                       \
    asm volatile("s_waitcnt vmcnt(" #N ")" ::: "memory");              \
    __builtin_amdgcn_sched_barrier(0)

__device__ __forceinline__ void gll16(const void* g, void* l) {
    __builtin_amdgcn_global_load_lds(
        (const __attribute__((address_space(1))) uint32_t*)g,
        (__attribute__((address_space(3))) uint32_t*)l, 16, 0, 0);
}

// Chunk c covers steps [8c, 8c+8); 4 instrs x 1024 B (chunk 31: 1 instr).
__device__ __forceinline__ void issue_chunk(const char* hg, char* ringb,
                                            int c, int n) {
    const char* g = hg + (size_t)c * 4096;
    char* l = ringb + (c & 3) * 4096;
    for (int i = 0; i < n; ++i) gll16(g + (size_t)i * 1024, l + i * 1024);
}

#define EXTR(K)                                                        \
    if (mlo) { K = (int)__ffsll(mlo) - 1; mlo &= mlo - 1ull; }         \
    else     { K = 64 + (int)__ffsll(mhi) - 1; mhi &= mhi - 1ull; }
#define EXTR2(K)                                                       \
    if (mlo)      { K = (int)__ffsll(mlo) - 1; mlo &= mlo - 1ull; }    \
    else if (mhi) { K = 64 + (int)__ffsll(mhi) - 1; mhi &= mhi - 1ull; }

// 4-index gather from rcW2: 8 dword loads (x at +0, y at +256B) and the
// retiring s_waitcnt fused in a single asm block. Outputs become visible to
// the compiler only after the wait -> no pending-register hazard.
#define GATHER4(D0X, D0Y, D1X, D1Y, D2X, D2Y, D3X, D3Y, P0, P1, P2, P3)       \
    asm volatile("global_load_dword %0, %8, off\n\t"                          \
                 "global_load_dword %1, %8, off offset:256\n\t"               \
                 "global_load_dword %2, %9, off\n\t"                          \
                 "global_load_dword %3, %9, off offset:256\n\t"               \
                 "global_load_dword %4, %10, off\n\t"                         \
                 "global_load_dword %5, %10, off offset:256\n\t"              \
                 "global_load_dword %6, %11, off\n\t"                         \
                 "global_load_dword %7, %11, off offset:256\n\t"              \
                 "s_waitcnt vmcnt(0)"                                         \
                 : "=&v"(D0X), "=&v"(D0Y), "=&v"(D1X), "=&v"(D1Y),            \
                   "=&v"(D2X), "=&v"(D2Y), "=&v"(D3X), "=&v"(D3Y)             \
                 : "v"(P0), "v"(P1), "v"(P2), "v"(P3)                         \
                 : "memory");

__global__ __launch_bounds__(64) void recurrent(
    const float* __restrict__ H1,   const float* __restrict__ rcW1,
    const float* __restrict__ rcb1, const float* __restrict__ W2,
    const float* __restrict__ b2,   const float* __restrict__ rcW2,
    const float* __restrict__ rcb2, const float* __restrict__ W3,
    const float* __restrict__ b3,   float* __restrict__ out) {

    __shared__ float W2ls[Hh * Hh];    // 64 KB
    __shared__ float rcW1ls[Hh * Hh];  // 64 KB
    __shared__ float ring[32 * Hh];    // 16 KB: 32 steps x 128 floats

    const int lane = threadIdx.x;     // 0..63
    const int b    = blockIdx.x;

    const float rcb1x = rcb1[lane], rcb1y = rcb1[lane + 64];
    const float bb2x  = b2[lane]      + rcb2[lane];
    const float bb2y  = b2[lane + 64] + rcb2[lane + 64];
    const float* __restrict__ h1p = H1 + (size_t)b * Tt * Hh;

    // async preload: W2, rcW1 -> LDS (linear copies), then ring chunks 0..2
    {
        const char* g2 = (const char*)W2 + lane * 16;
        const char* g1 = (const char*)rcW1 + lane * 16;
        char* l2 = (char*)W2ls;
        char* l1 = (char*)rcW1ls;
#pragma unroll 1
        for (int i = 0; i < 64; ++i) gll16(g2 + (size_t)i * 1024, l2 + i * 1024);
#pragma unroll 1
        for (int i = 0; i < 64; ++i) gll16(g1 + (size_t)i * 1024, l1 + i * 1024);
    }
    const char* hg = (const char*)h1p + lane * 16;
    char* ringb = (char*)ring;
    issue_chunk(hg, ringb, 0, 4);
    issue_chunk(hg, ringb, 1, 4);
    issue_chunk(hg, ringb, 2, 4);
    WAITV(4);   // weights + chunks 0,1 retired (in-order); chunk 2 in flight

    float v1x = 0.f, v1y = 0.f, v2x = 0.f, v2y = 0.f;
    float cntx = 0.f, cnty = 0.f;
    float u1gx = 0.f, u1gy = 0.f;     // rcW1 gather (valid iff sp1)
    float u2gx = 0.f, u2gy = 0.f;     // rcW2 gather (valid iff sp2)
    bool  sp1 = false, sp2 = false;

    // 4-deep register pipeline (slot j holds step t with t%4==j), from ring
    float h1xs[4], h1ys[4];
#pragma unroll
    for (int j = 0; j < 4; ++j) {
        h1xs[j] = ring[(j << 7) + lane];
        h1ys[j] = ring[(j << 7) + lane + 64];
    }

#define STEP(T, J)                                                            \
    {                                                                         \
        const int t_ = (T);                                                   \
        /* ---- LIF 1 (consume slot J, refill it for t+4 from ring) ---- */   \
        float u1xv = h1xs[J] + rcb1x;                                         \
        float u1yv = h1ys[J] + rcb1y;                                         \
        if (sp1) { u1xv += u1gx; u1yv += u1gy; }                              \
        int tp = t_ + 4; tp = (tp < Tt) ? tp : (Tt - 1);                      \
        const float* rp_ = &ring[(tp & 31) << 7];                             \
        h1xs[J] = rp_[lane];                                                  \
        h1ys[J] = rp_[lane + 64];                                             \
        v1x = v1x + (u1xv - v1x) * 0.5f;                                      \
        v1y = v1y + (u1yv - v1y) * 0.5f;                                      \
        const bool s1x = (v1x >= 1.0f);                                       \
        const bool s1y = (v1y >= 1.0f);                                       \
        if (s1x) v1x = 0.f;                                                   \
        if (s1y) v1y = 0.f;                                                   \
        const unsigned long long a0 = __ballot((int)s1x);                     \
        const unsigned long long a1 = __ballot((int)s1y);                     \
        /* ---- layer-1 fanout from LDS, 4-wide, ascending k, in-branch */    \
        float uW2x = 0.f, uW2y = 0.f;                                         \
        sp1 = ((a0 | a1) != 0ull);                                            \
        if (sp1) {                                                            \
            float g1x = 0.f, g1y = 0.f;                                       \
            unsigned long long mlo = a0, mhi = a1;                            \
            while (mlo | mhi) {                                               \
                int k0; int k1 = -1; int k2 = -1; int k3 = -1;                \
                EXTR(k0) EXTR2(k1) EXTR2(k2) EXTR2(k3)                        \
                const int i0 = k0 << 7;                                       \
                const int i1 = (k1 >= 0 ? k1 : k0) << 7;                      \
                const int i2 = (k2 >= 0 ? k2 : k0) << 7;                      \
                const int i3 = (k3 >= 0 ? k3 : k0) << 7;                      \
                const float w0x = W2ls[i0 + lane],   w0y = W2ls[i0 + 64 + lane];   \
                const float r0x = rcW1ls[i0 + lane], r0y = rcW1ls[i0 + 64 + lane]; \
                const float w1x = W2ls[i1 + lane],   w1y = W2ls[i1 + 64 + lane];   \
                const float r1x = rcW1ls[i1 + lane], r1y = rcW1ls[i1 + 64 + lane]; \
                const float w2x = W2ls[i2 + lane],   w2y = W2ls[i2 + 64 + lane];   \
                const float r2x = rcW1ls[i2 + lane], r2y = rcW1ls[i2 + 64 + lane]; \
                const float w3x = W2ls[i3 + lane],   w3y = W2ls[i3 + 64 + lane];   \
                const float r3x = rcW1ls[i3 + lane], r3y = rcW1ls[i3 + 64 + lane]; \
                uW2x += w0x; uW2y += w0y; g1x += r0x; g1y += r0y;             \
                if (k1 >= 0) { uW2x += w1x; uW2y += w1y; g1x += r1x; g1y += r1y; } \
                if (k2 >= 0) { uW2x += w2x; uW2y += w2y; g1x += r2x; g1y += r2y; } \
                if (k3 >= 0) { uW2x += w3x; uW2y += w3y; g1x += r3x; g1y += r3y; } \
            }                                                                 \
            u1gx = g1x; u1gy = g1y;                                           \
        }                                                                     \
        /* ---- LIF 2 (apply prev-step rcW2 gather under sp2 guard) ---- */   \
        float u2xv = bb2x + uW2x;                                             \
        float u2yv = bb2y + uW2y;                                             \
        if (sp2) { u2xv += u2gx; u2yv += u2gy; }                              \
        v2x = v2x + (u2xv - v2x) * 0.5f;                                      \
        v2y = v2y + (u2yv - v2y) * 0.5f;                                      \
        const bool s2x = (v2x >= 1.0f);                                       \
        const bool s2y = (v2y >= 1.0f);                                       \
        if (s2x) v2x = 0.f;                                                   \
        if (s2y) v2y = 0.f;                                                   \
        cntx += s2x ? 1.f : 0.f;                                              \
        cnty += s2y ? 1.f : 0.f;                                              \
        const unsigned long long c0m = __ballot((int)s2x);                    \
        const unsigned long long c1m = __ballot((int)s2y);                    \
        /* ---- layer-2 rcW2 gather: fused asm load+wait, ascending k ---- */ \
        sp2 = ((c0m | c1m) != 0ull);                                          \
        if (sp2) {                                                            \
            float sx = 0.f, sy = 0.f;                                         \
            unsigned long long mlo = c0m, mhi = c1m;                          \
            while (mlo | mhi) {                                               \
                int k0; int k1 = -1; int k2 = -1; int k3 = -1;                \
                EXTR(k0) EXTR2(k1) EXTR2(k2) EXTR2(k3)                        \
                const float* p0 = rcW2 + ((size_t)k0 << 7) + lane;            \
                const float* p1 =                                             \
                    rcW2 + ((size_t)(k1 >= 0 ? k1 : k0) << 7) + lane;         \
                const float* p2 =                                             \
                    rcW2 + ((size_t)(k2 >= 0 ? k2 : k0) << 7) + lane;         \
                const float* p3 =                                             \
                    rcW2 + ((size_t)(k3 >= 0 ? k3 : k0) << 7) + lane;         \
                float d0x, d0y, d1x, d1y, d2x, d2y, d3x, d3y;                 \
                GATHER4(d0x, d0y, d1x, d1y, d2x, d2y, d3x, d3y,               \
                        p0, p1, p2, p3)                                       \
                sx += d0x; sy += d0y;                                         \
                if (k1 >= 0) { sx += d1x; sy += d1y; }                        \
                if (k2 >= 0) { sx += d2x; sy += d2y; }                        \
                if (k3 >= 0) { sx += d3x; sy += d3y; }                        \
            }                                                                 \
            u2gx = sx; u2gy = sy;                                             \
        }                                                                     \
    }

    // Main loop: 31 chunks x 8 steps (t=0..247), then tail 248,249.
    // vmcnt at boundaries: after issuing chunk c+3, at most chunks c+2 and
    // c+3 (8 loads) are outstanding (gather asm drains to 0 internally), so
    // WAITV(8) guarantees chunk c+1 retired before its steps consume it.
#pragma unroll 1
    for (int c = 0; c < 31; ++c) {
        if (c <= 27)      issue_chunk(hg, ringb, c + 3, 4);
        else if (c == 28) issue_chunk(hg, ringb, 31, 1);
        if (c <= 27) { WAITV(8); } else { WAITV(0); }
        const int t0 = c << 3;
#pragma unroll 1
        for (int g = 0; g < 2; ++g) {
            const int t = t0 + (g << 2);
            STEP(t + 0, 0)
            STEP(t + 1, 1)
            STEP(t + 2, 2)
            STEP(t + 3, 3)
        }
    }
    WAITV(0);
    STEP(248, 0)
    STEP(249, 1)
#undef STEP

    // ---- readout: out[b] = cnt2 @ W3 + T*b3 (ring reused as scratch) ----
    __syncthreads();
    ring[lane]      = cntx;
    ring[lane + 64] = cnty;
    __syncthreads();
    if (lane < DOUT) {
        float o = (float)Tt * b3[lane];
#pragma unroll 8
        for (int k = 0; k < Hh; ++k) o += ring[k] * W3[k * DOUT + lane];
        out[b * DOUT + lane] = o;
    }
}

// ---------------------------------------------------------------------------
extern "C" void kernel_launch(void* const* d_in, const int* in_sizes, int n_in,
                              void* d_out, int out_size, void* d_ws, size_t ws_size,
                              hipStream_t stream) {
    const float* x    = (const float*)d_in[0];
    const float* W1   = (const float*)d_in[1];
    const float* b1   = (const float*)d_in[2];
    const float* rcW1 = (const float*)d_in[3];
    const float* rcb1 = (const float*)d_in[4];
    const float* W2   = (const float*)d_in[5];
    const float* b2   = (const float*)d_in[6];
    const float* rcW2 = (const float*)d_in[7];
    const float* rcb2 = (const float*)d_in[8];
    const float* W3   = (const float*)d_in[9];
    const float* b3   = (const float*)d_in[10];

    float* out = (float*)d_out;
    float* H1  = (float*)d_ws;   // 64000 x 128 f32 = 32.77 MB

    gemm_h1<<<(Bb * Tt) / BM, 256, 0, stream>>>(x, W1, b1, H1);
    recurrent<<<Bb, 64, 0, stream>>>(H1, rcW1, rcb1, W2, b2, rcW2, rcb2, W3,
                                     b3, out);
}

// Round 9
// 450.904 us; speedup vs baseline: 2.3029x; 1.0251x over previous
//
#include <hip/hip_runtime.h>
#include <cstdint>
#include <cstddef>

// Problem constants (match reference setup_inputs)
#define Bb   256
#define Tt   250
#define DIN  700
#define Hh   128
#define DOUT 20

// ---------------------------------------------------------------------------
// Phase 1: EXACT R0 gemm (218 us, VGPR 92, verified). Do not touch.
// ---------------------------------------------------------------------------
constexpr int BM  = 128;
constexpr int BK  = 20;
constexpr int BN  = 128;
constexpr int BMP = BM + 4;

__device__ __forceinline__ int bswz(int g) { return g ^ (g >> 3); }

__global__ __launch_bounds__(256, 2) void gemm_h1(const float* __restrict__ x,
                                                  const float* __restrict__ W1,
                                                  const float* __restrict__ b1,
                                                  float* __restrict__ H1) {
    __shared__ float Ast[BK][BMP];
    __shared__ float Bs[BK][BN];

    const int tid = threadIdx.x;
    const int tx  = tid & 15;
    const int ty  = tid >> 4;
    const int m0  = blockIdx.x * BM;

    const int c0 = bswz(tx * 2) * 4;
    const int c1 = bswz(tx * 2 + 1) * 4;

    float acc[8][8];
#pragma unroll
    for (int r = 0; r < 8; ++r)
#pragma unroll
        for (int c = 0; c < 8; ++c) acc[r][c] = 0.f;

    for (int k0 = 0; k0 < DIN; k0 += BK) {
#pragma unroll
        for (int idx = tid; idx < 640; idx += 256) {
            int row = idx / 5;
            int kq  = (idx - row * 5) * 4;
            const float4 v =
                *(const float4*)&x[(size_t)(m0 + row) * DIN + (k0 + kq)];
            Ast[kq + 0][row] = v.x;
            Ast[kq + 1][row] = v.y;
            Ast[kq + 2][row] = v.z;
            Ast[kq + 3][row] = v.w;
        }
#pragma unroll
        for (int idx = tid; idx < 640; idx += 256) {
            int kr = idx >> 5;
            int g  = idx & 31;
            *(float4*)&Bs[kr][bswz(g) * 4] =
                *(const float4*)&W1[(size_t)(k0 + kr) * BN + g * 4];
        }
        __syncthreads();

#pragma unroll
        for (int kk = 0; kk < BK; ++kk) {
            float a[8], bv[8];
            *(float4*)&a[0]  = *(const float4*)&Ast[kk][ty * 8];
            *(float4*)&a[4]  = *(const float4*)&Ast[kk][ty * 8 + 4];
            *(float4*)&bv[0] = *(const float4*)&Bs[kk][c0];
            *(float4*)&bv[4] = *(const float4*)&Bs[kk][c1];
#pragma unroll
            for (int r = 0; r < 8; ++r)
#pragma unroll
                for (int c = 0; c < 8; ++c)
                    acc[r][c] = fmaf(a[r], bv[c], acc[r][c]);
        }
        __syncthreads();
    }

    float bb[8];
#pragma unroll
    for (int c = 0; c < 8; ++c) bb[c] = b1[tx * 8 + c];

#pragma unroll
    for (int r = 0; r < 8; ++r) {
        size_t row = (size_t)(m0 + ty * 8 + r);
        float4 o0, o1;
        o0.x = acc[r][0] + bb[0]; o0.y = acc[r][1] + bb[1];
        o0.z = acc[r][2] + bb[2]; o0.w = acc[r][3] + bb[3];
        o1.x = acc[r][4] + bb[4]; o1.y = acc[r][5] + bb[5];
        o1.z = acc[r][6] + bb[6]; o1.w = acc[r][7] + bb[7];
        *(float4*)&H1[row * Hh + tx * 8]     = o0;
        *(float4*)&H1[row * Hh + tx * 8 + 4] = o1;
    }
}

// ---------------------------------------------------------------------------
// Phase 2: recurrence, preamble-free. (Resubmission of R8 — container-level
// infra failure, same signature as R1 which later proved to be a flake; the
// kernel was re-audited: all addresses in bounds, no deadlock mechanism, asm
// macro byte-identical to R7's verified one.)
// R5's dispatch arithmetic (rec12=601, rec1=217 -> pass=35us, launch-part
// ~181us) showed the 128KB W2+rcW1->LDS preload WAS the dominant cost of
// R3/R5/R6/R7; R0/R2 were separately slow from per-step compiler waitcnt
// drains on plain-C in-loop loads. This kernel avoids both families:
//  - NO weight staging at all (no preamble). Spikes are rare (~0.2/step),
//    so W2/rcW1 are gathered straight from global (L2-resident, 128KB)
//    inside the spike branch via fused asm (loads + s_waitcnt vmcnt(0) in
//    ONE asm block -> no pending-register hazard; mechanism verified by
//    R7's absmax 0.0 on the rcW2 path).
//  - h1 via the R2/R3/R6/R7-verified LDS ring (global_load_lds + counted
//    WAITV(8) at 8-step chunk boundaries).
//  - layer-2 rcW2: EXACT R7 deferred fused-asm gather (verified).
// All summation trees keep the verified left-fold ascending-k order;
// sp1/sp2 guards skip exact +0.0f terms only => absmax 0.0.
// ---------------------------------------------------------------------------

#define WAITV(N)                                                       \
    asm volatile("s_waitcnt vmcnt(" #N ")" ::: "memory");              \
    __builtin_amdgcn_sched_barrier(0)

__device__ __forceinline__ void gll16(const void* g, void* l) {
    __builtin_amdgcn_global_load_lds(
        (const __attribute__((address_space(1))) uint32_t*)g,
        (__attribute__((address_space(3))) uint32_t*)l, 16, 0, 0);
}

// Chunk c covers steps [8c, 8c+8); 4 instrs x 1024 B (chunk 31: 1 instr).
__device__ __forceinline__ void issue_chunk(const char* hg, char* ringb,
                                            int c, int n) {
    const char* g = hg + (size_t)c * 4096;
    char* l = ringb + (c & 3) * 4096;
    for (int i = 0; i < n; ++i) gll16(g + (size_t)i * 1024, l + i * 1024);
}

#define EXTR(K)                                                        \
    if (mlo) { K = (int)__ffsll(mlo) - 1; mlo &= mlo - 1ull; }         \
    else     { K = 64 + (int)__ffsll(mhi) - 1; mhi &= mhi - 1ull; }
#define EXTR2(K)                                                       \
    if (mlo)      { K = (int)__ffsll(mlo) - 1; mlo &= mlo - 1ull; }    \
    else if (mhi) { K = 64 + (int)__ffsll(mhi) - 1; mhi &= mhi - 1ull; }

// 8 dword loads from 4 row pointers (x at +0, y at +256B) and the retiring
// s_waitcnt fused in ONE asm block: destination regs are unobservable until
// retired -> no pending-register hazard (R7-verified mechanism).
#define GATHER4(D0X, D0Y, D1X, D1Y, D2X, D2Y, D3X, D3Y, P0, P1, P2, P3)       \
    asm volatile("global_load_dword %0, %8, off\n\t"                          \
                 "global_load_dword %1, %8, off offset:256\n\t"               \
                 "global_load_dword %2, %9, off\n\t"                          \
                 "global_load_dword %3, %9, off offset:256\n\t"               \
                 "global_load_dword %4, %10, off\n\t"                         \
                 "global_load_dword %5, %10, off offset:256\n\t"              \
                 "global_load_dword %6, %11, off\n\t"                         \
                 "global_load_dword %7, %11, off offset:256\n\t"              \
                 "s_waitcnt vmcnt(0)"                                         \
                 : "=&v"(D0X), "=&v"(D0Y), "=&v"(D1X), "=&v"(D1Y),            \
                   "=&v"(D2X), "=&v"(D2Y), "=&v"(D3X), "=&v"(D3Y)             \
                 : "v"(P0), "v"(P1), "v"(P2), "v"(P3)                         \
                 : "memory");

__global__ __launch_bounds__(64) void recurrent(
    const float* __restrict__ H1,   const float* __restrict__ rcW1,
    const float* __restrict__ rcb1, const float* __restrict__ W2,
    const float* __restrict__ b2,   const float* __restrict__ rcW2,
    const float* __restrict__ rcb2, const float* __restrict__ W3,
    const float* __restrict__ b3,   float* __restrict__ out) {

    __shared__ float ring[32 * Hh];    // 16 KB: 32 steps x 128 floats

    const int lane = threadIdx.x;     // 0..63
    const int b    = blockIdx.x;

    const float rcb1x = rcb1[lane], rcb1y = rcb1[lane + 64];
    const float bb2x  = b2[lane]      + rcb2[lane];
    const float bb2y  = b2[lane + 64] + rcb2[lane + 64];
    const float* __restrict__ h1p = H1 + (size_t)b * Tt * Hh;

    const char* hg = (const char*)h1p + lane * 16;
    char* ringb = (char*)ring;
    issue_chunk(hg, ringb, 0, 4);
    issue_chunk(hg, ringb, 1, 4);
    issue_chunk(hg, ringb, 2, 4);
    WAITV(4);   // chunks 0,1 retired (in-order); chunk 2 in flight

    float v1x = 0.f, v1y = 0.f, v2x = 0.f, v2y = 0.f;
    float cntx = 0.f, cnty = 0.f;
    float u1gx = 0.f, u1gy = 0.f;     // rcW1 gather (valid iff sp1)
    float u2gx = 0.f, u2gy = 0.f;     // rcW2 gather (valid iff sp2)
    bool  sp1 = false, sp2 = false;

    // 4-deep register pipeline (slot j holds step t with t%4==j), from ring
    float h1xs[4], h1ys[4];
#pragma unroll
    for (int j = 0; j < 4; ++j) {
        h1xs[j] = ring[(j << 7) + lane];
        h1ys[j] = ring[(j << 7) + lane + 64];
    }

#define STEP(T, J)                                                            \
    {                                                                         \
        const int t_ = (T);                                                   \
        /* ---- LIF 1 (consume slot J, refill it for t+4 from ring) ---- */   \
        float u1xv = h1xs[J] + rcb1x;                                         \
        float u1yv = h1ys[J] + rcb1y;                                         \
        if (sp1) { u1xv += u1gx; u1yv += u1gy; }                              \
        int tp = t_ + 4; tp = (tp < Tt) ? tp : (Tt - 1);                      \
        const float* rp_ = &ring[(tp & 31) << 7];                             \
        h1xs[J] = rp_[lane];                                                  \
        h1ys[J] = rp_[lane + 64];                                             \
        v1x = v1x + (u1xv - v1x) * 0.5f;                                      \
        v1y = v1y + (u1yv - v1y) * 0.5f;                                      \
        const bool s1x = (v1x >= 1.0f);                                       \
        const bool s1y = (v1y >= 1.0f);                                       \
        if (s1x) v1x = 0.f;                                                   \
        if (s1y) v1y = 0.f;                                                   \
        const unsigned long long a0 = __ballot((int)s1x);                     \
        const unsigned long long a1 = __ballot((int)s1y);                     \
        /* ---- layer-1 fanout: W2 + rcW1 straight from global, fused asm,    \
           2 spike-indices per round, ascending k, left-fold ---- */          \
        float uW2x = 0.f, uW2y = 0.f;                                         \
        sp1 = ((a0 | a1) != 0ull);                                            \
        if (sp1) {                                                            \
            float g1x = 0.f, g1y = 0.f;                                       \
            unsigned long long mlo = a0, mhi = a1;                            \
            while (mlo | mhi) {                                               \
                int k0; int k1 = -1;                                          \
                EXTR(k0) EXTR2(k1)                                            \
                const int kb = (k1 >= 0 ? k1 : k0);                           \
                const float* pw0 = W2   + ((size_t)k0 << 7) + lane;           \
                const float* pr0 = rcW1 + ((size_t)k0 << 7) + lane;           \
                const float* pw1 = W2   + ((size_t)kb << 7) + lane;           \
                const float* pr1 = rcW1 + ((size_t)kb << 7) + lane;           \
                float w0x, w0y, r0x, r0y, w1x, w1y, r1x, r1y;                 \
                GATHER4(w0x, w0y, r0x, r0y, w1x, w1y, r1x, r1y,               \
                        pw0, pr0, pw1, pr1)                                   \
                uW2x += w0x; uW2y += w0y; g1x += r0x; g1y += r0y;             \
                if (k1 >= 0) {                                                \
                    uW2x += w1x; uW2y += w1y; g1x += r1x; g1y += r1y;         \
                }                                                             \
            }                                                                 \
            u1gx = g1x; u1gy = g1y;                                           \
        }                                                                     \
        /* ---- LIF 2 (apply prev-step rcW2 gather under sp2 guard) ---- */   \
        float u2xv = bb2x + uW2x;                                             \
        float u2yv = bb2y + uW2y;                                             \
        if (sp2) { u2xv += u2gx; u2yv += u2gy; }                              \
        v2x = v2x + (u2xv - v2x) * 0.5f;                                      \
        v2y = v2y + (u2yv - v2y) * 0.5f;                                      \
        const bool s2x = (v2x >= 1.0f);                                       \
        const bool s2y = (v2y >= 1.0f);                                       \
        if (s2x) v2x = 0.f;                                                   \
        if (s2y) v2y = 0.f;                                                   \
        cntx += s2x ? 1.f : 0.f;                                              \
        cnty += s2y ? 1.f : 0.f;                                              \
        const unsigned long long c0m = __ballot((int)s2x);                    \
        const unsigned long long c1m = __ballot((int)s2y);                    \
        /* ---- layer-2 rcW2 gather: EXACT R7 fused asm, ascending k ---- */  \
        sp2 = ((c0m | c1m) != 0ull);                                          \
        if (sp2) {                                                            \
            float sx = 0.f, sy = 0.f;                                         \
            unsigned long long mlo = c0m, mhi = c1m;                          \
            while (mlo | mhi) {                                               \
                int k0; int k1 = -1; int k2 = -1; int k3 = -1;                \
                EXTR(k0) EXTR2(k1) EXTR2(k2) EXTR2(k3)                        \
                const float* p0 = rcW2 + ((size_t)k0 << 7) + lane;            \
                const float* p1 =                                             \
                    rcW2 + ((size_t)(k1 >= 0 ? k1 : k0) << 7) + lane;         \
                const float* p2 =                                             \
                    rcW2 + ((size_t)(k2 >= 0 ? k2 : k0) << 7) + lane;         \
                const float* p3 =                                             \
                    rcW2 + ((size_t)(k3 >= 0 ? k3 : k0) << 7) + lane;         \
                float d0x, d0y, d1x, d1y, d2x, d2y, d3x, d3y;                 \
                GATHER4(d0x, d0y, d1x, d1y, d2x, d2y, d3x, d3y,               \
                        p0, p1, p2, p3)                                       \
                sx += d0x; sy += d0y;                                         \
                if (k1 >= 0) { sx += d1x; sy += d1y; }                        \
                if (k2 >= 0) { sx += d2x; sy += d2y; }                        \
                if (k3 >= 0) { sx += d3x; sy += d3y; }                        \
            }                                                                 \
            u2gx = sx; u2gy = sy;                                             \
        }                                                                     \
    }

    // Main loop: 31 chunks x 8 steps (t=0..247), then tail 248,249.
    // vmcnt at boundaries: after issuing chunk c+3, at most chunks c+1..c+3
    // (12 loads) outstanding (gather asm drains to 0 internally), so
    // WAITV(8) guarantees chunk c+1 retired before its steps consume it.
#pragma unroll 1
    for (int c = 0; c < 31; ++c) {
        if (c <= 27)      issue_chunk(hg, ringb, c + 3, 4);
        else if (c == 28) issue_chunk(hg, ringb, 31, 1);
        if (c <= 27) { WAITV(8); } else { WAITV(0); }
        const int t0 = c << 3;
#pragma unroll 1
        for (int g = 0; g < 2; ++g) {
            const int t = t0 + (g << 2);
            STEP(t + 0, 0)
            STEP(t + 1, 1)
            STEP(t + 2, 2)
            STEP(t + 3, 3)
        }
    }
    WAITV(0);
    STEP(248, 0)
    STEP(249, 1)
#undef STEP

    // ---- readout: out[b] = cnt2 @ W3 + T*b3 (ring reused as scratch) ----
    __syncthreads();
    ring[lane]      = cntx;
    ring[lane + 64] = cnty;
    __syncthreads();
    if (lane < DOUT) {
        float o = (float)Tt * b3[lane];
#pragma unroll 8
        for (int k = 0; k < Hh; ++k) o += ring[k] * W3[k * DOUT + lane];
        out[b * DOUT + lane] = o;
    }
}

// ---------------------------------------------------------------------------
extern "C" void kernel_launch(void* const* d_in, const int* in_sizes, int n_in,
                              void* d_out, int out_size, void* d_ws, size_t ws_size,
                              hipStream_t stream) {
    const float* x    = (const float*)d_in[0];
    const float* W1   = (const float*)d_in[1];
    const float* b1   = (const float*)d_in[2];
    const float* rcW1 = (const float*)d_in[3];
    const float* rcb1 = (const float*)d_in[4];
    const float* W2   = (const float*)d_in[5];
    const float* b2   = (const float*)d_in[6];
    const float* rcW2 = (const float*)d_in[7];
    const float* rcb2 = (const float*)d_in[8];
    const float* W3   = (const float*)d_in[9];
    const float* b3   = (const float*)d_in[10];

    float* out = (float*)d_out;
    float* H1  = (float*)d_ws;   // 64000 x 128 f32 = 32.77 MB

    gemm_h1<<<(Bb * Tt) / BM, 256, 0, stream>>>(x, W1, b1, H1);
    recurrent<<<Bb, 64, 0, stream>>>(H1, rcW1, rcb1, W2, b2, rcW2, rcb2, W3,
                                     b3, out);
}